// Round 5
// baseline (250.955 us; speedup 1.0000x reference)
//
#include <hip/hip_runtime.h>
#include <hip/hip_cooperative_groups.h>

namespace cg = cooperative_groups;

static constexpr int kNodes = 100000;
static constexpr int kEdges = 1600000;
static constexpr int kD     = 128;

typedef float fx4 __attribute__((ext_vector_type(4)));

// ---------------------------------------------------------------------------
// Fused kernel: phase 1 (per-node partial dots into h) -> grid sync ->
// phase 2 (per-edge gather + 2-way softmax). Persistent grid, cooperative
// launch. W is loaded once per thread into registers (amortized over ~6
// nodes/group), no nontemporal hints anywhere (inputs are L3-resident
// across graph replays).
// ---------------------------------------------------------------------------
__global__ __launch_bounds__(256, 4) void fused(const float* __restrict__ emb,
                                                const void* __restrict__ eiv,
                                                const float* __restrict__ W,
                                                const float* __restrict__ b,
                                                float* __restrict__ h,
                                                float* __restrict__ out) {
    const int tid      = blockIdx.x * blockDim.x + threadIdx.x;
    const int nthreads = gridDim.x * blockDim.x;
    const int l  = threadIdx.x & 15;   // lane within 16-group
    const int c0 = l * 8;

    // ---- phase 1: h[n] = {e·W0[:128], e·W1[:128], e·W0[128:], e·W1[128:]} ----
    {
        fx4 w0a = *(const fx4*)&W[c0],       w0b = *(const fx4*)&W[c0 + 4];
        fx4 w1a = *(const fx4*)&W[256 + c0], w1b = *(const fx4*)&W[256 + c0 + 4];
        fx4 w2a = *(const fx4*)&W[128 + c0], w2b = *(const fx4*)&W[128 + c0 + 4];
        fx4 w3a = *(const fx4*)&W[384 + c0], w3b = *(const fx4*)&W[384 + c0 + 4];

        const int group   = tid >> 4;
        const int ngroups = nthreads >> 4;

        for (int n = group; n < kNodes; n += ngroups) {
            const fx4* row = (const fx4*)(emb + (size_t)n * kD + c0);
            fx4 ea = row[0];
            fx4 eb = row[1];

            float p0 = ea.x*w0a.x + ea.y*w0a.y + ea.z*w0a.z + ea.w*w0a.w
                     + eb.x*w0b.x + eb.y*w0b.y + eb.z*w0b.z + eb.w*w0b.w;
            float p1 = ea.x*w1a.x + ea.y*w1a.y + ea.z*w1a.z + ea.w*w1a.w
                     + eb.x*w1b.x + eb.y*w1b.y + eb.z*w1b.z + eb.w*w1b.w;
            float p2 = ea.x*w2a.x + ea.y*w2a.y + ea.z*w2a.z + ea.w*w2a.w
                     + eb.x*w2b.x + eb.y*w2b.y + eb.z*w2b.z + eb.w*w2b.w;
            float p3 = ea.x*w3a.x + ea.y*w3a.y + ea.z*w3a.z + ea.w*w3a.w
                     + eb.x*w3b.x + eb.y*w3b.y + eb.z*w3b.z + eb.w*w3b.w;

#pragma unroll
            for (int m = 1; m < 16; m <<= 1) {
                p0 += __shfl_xor(p0, m, 64);
                p1 += __shfl_xor(p1, m, 64);
                p2 += __shfl_xor(p2, m, 64);
                p3 += __shfl_xor(p3, m, 64);
            }
            if (l == 0) {
                fx4 v = {p0, p1, p2, p3};
                ((fx4*)h)[n] = v;
            }
        }
    }

    // ---- grid-wide barrier with device-scope release/acquire ----
    __threadfence();             // release: write back h (cross-XCD visibility)
    cg::this_grid().sync();
    __threadfence();             // acquire: invalidate any stale h lines

    // ---- phase 2: per-edge gather + softmax, 2 edges/thread ----
    const unsigned long long* ei64 = (const unsigned long long*)eiv;
    unsigned long long hi = ei64[threadIdx.x & 63] >> 32;
    const bool is64 = (__ballot(hi != 0ull) == 0ull);

    const float b0 = b[0], b1 = b[1];
    const fx4* h4 = (const fx4*)h;

    for (int e2 = tid; e2 < kEdges / 2; e2 += nthreads) {
        int r0, r1, c0i, c1i;
        if (is64) {
            const unsigned long long* rr = ei64 + 2 * e2;
            const unsigned long long* cc = ei64 + kEdges + 2 * e2;
            r0  = (int)rr[0]; r1  = (int)rr[1];
            c0i = (int)cc[0]; c1i = (int)cc[1];
        } else {
            const int* ei32 = (const int*)eiv;
            r0  = ei32[2 * e2];          r1  = ei32[2 * e2 + 1];
            c0i = ei32[kEdges + 2 * e2]; c1i = ei32[kEdges + 2 * e2 + 1];
        }

        fx4 hr0 = h4[r0];
        fx4 hc0 = h4[c0i];
        fx4 hr1 = h4[r1];
        fx4 hc1 = h4[c1i];

        float s00 = hr0.x + hc0.z + b0;
        float s01 = hr0.y + hc0.w + b1;
        float m0  = fmaxf(s00, s01);
        float x00 = __expf(s00 - m0);
        float x01 = __expf(s01 - m0);
        float i0  = 1.0f / (x00 + x01);

        float s10 = hr1.x + hc1.z + b0;
        float s11 = hr1.y + hc1.w + b1;
        float m1  = fmaxf(s10, s11);
        float x10 = __expf(s10 - m1);
        float x11 = __expf(s11 - m1);
        float i1  = 1.0f / (x10 + x11);

        fx4 o = {x00 * i0, x01 * i0, x10 * i1, x11 * i1};
        ((fx4*)out)[e2] = o;
    }
}

// ---------------------------------------------------------------------------
// Fallback path (two plain launches) in case cooperative launch is rejected.
// ---------------------------------------------------------------------------
__global__ __launch_bounds__(256) void node_pre(const float* __restrict__ emb,
                                                const float* __restrict__ W,
                                                float* __restrict__ h) {
    const int l  = threadIdx.x & 15;
    const int c0 = l * 8;

    fx4 w0a = *(const fx4*)&W[c0],       w0b = *(const fx4*)&W[c0 + 4];
    fx4 w1a = *(const fx4*)&W[256 + c0], w1b = *(const fx4*)&W[256 + c0 + 4];
    fx4 w2a = *(const fx4*)&W[128 + c0], w2b = *(const fx4*)&W[128 + c0 + 4];
    fx4 w3a = *(const fx4*)&W[384 + c0], w3b = *(const fx4*)&W[384 + c0 + 4];

    const int n = (blockIdx.x * blockDim.x + threadIdx.x) >> 4;
    if (n >= kNodes) return;

    const fx4* row = (const fx4*)(emb + (size_t)n * kD + c0);
    fx4 ea = row[0];
    fx4 eb = row[1];

    float p0 = ea.x*w0a.x + ea.y*w0a.y + ea.z*w0a.z + ea.w*w0a.w
             + eb.x*w0b.x + eb.y*w0b.y + eb.z*w0b.z + eb.w*w0b.w;
    float p1 = ea.x*w1a.x + ea.y*w1a.y + ea.z*w1a.z + ea.w*w1a.w
             + eb.x*w1b.x + eb.y*w1b.y + eb.z*w1b.z + eb.w*w1b.w;
    float p2 = ea.x*w2a.x + ea.y*w2a.y + ea.z*w2a.z + ea.w*w2a.w
             + eb.x*w2b.x + eb.y*w2b.y + eb.z*w2b.z + eb.w*w2b.w;
    float p3 = ea.x*w3a.x + ea.y*w3a.y + ea.z*w3a.z + ea.w*w3a.w
             + eb.x*w3b.x + eb.y*w3b.y + eb.z*w3b.z + eb.w*w3b.w;

#pragma unroll
    for (int m = 1; m < 16; m <<= 1) {
        p0 += __shfl_xor(p0, m, 64);
        p1 += __shfl_xor(p1, m, 64);
        p2 += __shfl_xor(p2, m, 64);
        p3 += __shfl_xor(p3, m, 64);
    }
    if (l == 0) {
        fx4 v = {p0, p1, p2, p3};
        ((fx4*)h)[n] = v;
    }
}

__global__ __launch_bounds__(256) void edge_attn(const void* __restrict__ eiv,
                                                 const float* __restrict__ h,
                                                 const float* __restrict__ b,
                                                 float* __restrict__ out) {
    const unsigned long long* ei64 = (const unsigned long long*)eiv;
    unsigned long long hi = ei64[threadIdx.x & 63] >> 32;
    const bool is64 = (__ballot(hi != 0ull) == 0ull);

    const int e2 = blockIdx.x * blockDim.x + threadIdx.x;
    if (e2 >= kEdges / 2) return;

    int r0, r1, c0i, c1i;
    if (is64) {
        const unsigned long long* rr = ei64 + 2 * e2;
        const unsigned long long* cc = ei64 + kEdges + 2 * e2;
        r0  = (int)rr[0]; r1  = (int)rr[1];
        c0i = (int)cc[0]; c1i = (int)cc[1];
    } else {
        const int* ei32 = (const int*)eiv;
        r0  = ei32[2 * e2];          r1  = ei32[2 * e2 + 1];
        c0i = ei32[kEdges + 2 * e2]; c1i = ei32[kEdges + 2 * e2 + 1];
    }

    const fx4* h4 = (const fx4*)h;
    fx4 hr0 = h4[r0];
    fx4 hc0 = h4[c0i];
    fx4 hr1 = h4[r1];
    fx4 hc1 = h4[c1i];

    const float b0 = b[0], b1 = b[1];

    float s00 = hr0.x + hc0.z + b0;
    float s01 = hr0.y + hc0.w + b1;
    float m0  = fmaxf(s00, s01);
    float x00 = __expf(s00 - m0);
    float x01 = __expf(s01 - m0);
    float i0  = 1.0f / (x00 + x01);

    float s10 = hr1.x + hc1.z + b0;
    float s11 = hr1.y + hc1.w + b1;
    float m1  = fmaxf(s10, s11);
    float x10 = __expf(s10 - m1);
    float x11 = __expf(s11 - m1);
    float i1  = 1.0f / (x10 + x11);

    fx4 o = {x00 * i0, x01 * i0, x10 * i1, x11 * i1};
    ((fx4*)out)[e2] = o;
}

extern "C" void kernel_launch(void* const* d_in, const int* in_sizes, int n_in,
                              void* d_out, int out_size, void* d_ws, size_t ws_size,
                              hipStream_t stream) {
    const float* emb = (const float*)d_in[0];
    const void*  ei  = d_in[1];
    const float* W   = (const float*)d_in[2];
    const float* b   = (const float*)d_in[3];
    float* out = (float*)d_out;
    float* h   = (float*)d_ws;   // 1.6 MB node table

    void* args[] = {(void*)&emb, (void*)&ei, (void*)&W, (void*)&b,
                    (void*)&h, (void*)&out};
    hipError_t err = hipLaunchCooperativeKernel((const void*)fused,
                                                dim3(1024), dim3(256),
                                                args, 0, stream);
    if (err != hipSuccess) {
        // fallback: two plain launches
        node_pre<<<(kNodes * 16 + 255) / 256, 256, 0, stream>>>(emb, W, h);
        edge_attn<<<(kEdges / 2 + 255) / 256, 256, 0, stream>>>(ei, h, b, out);
    }
}

// Round 6
// 33.360 us; speedup vs baseline: 7.5227x; 7.5227x over previous
//
#include <hip/hip_runtime.h>

static constexpr int kNodes = 100000;
static constexpr int kEdges = 1600000;
static constexpr int kD     = 128;

typedef float fx4 __attribute__((ext_vector_type(4)));

// ---------------------------------------------------------------------------
// Phase 1: per-node partial dot products.
// h[n] = { emb[n]·W[0][0:128], emb[n]·W[1][0:128],
//          emb[n]·W[0][128:256], emb[n]·W[1][128:256] }
// 16 lanes per node, 8 columns per lane, W slices in registers (fx4 loads),
// ~4 nodes per group via grid-stride (amortizes W load / L1 broadcast
// traffic). 5-shuffle transpose-reduce leaves output j on lane j (j<4),
// stored as a contiguous 16B chunk. NO nontemporal hints: inputs are
// L3-resident across graph replays and must stay cacheable.
// ---------------------------------------------------------------------------
__global__ __launch_bounds__(256) void node_pre(const float* __restrict__ emb,
                                                const float* __restrict__ W,
                                                float* __restrict__ h) {
    const int l  = threadIdx.x & 15;   // lane within 16-group
    const int c0 = l * 8;

    fx4 w0a = *(const fx4*)&W[c0],       w0b = *(const fx4*)&W[c0 + 4];
    fx4 w1a = *(const fx4*)&W[256 + c0], w1b = *(const fx4*)&W[256 + c0 + 4];
    fx4 w2a = *(const fx4*)&W[128 + c0], w2b = *(const fx4*)&W[128 + c0 + 4];
    fx4 w3a = *(const fx4*)&W[384 + c0], w3b = *(const fx4*)&W[384 + c0 + 4];

    const int group   = (blockIdx.x * blockDim.x + threadIdx.x) >> 4;
    const int ngroups = (gridDim.x * blockDim.x) >> 4;

    for (int n = group; n < kNodes; n += ngroups) {
        const fx4* row = (const fx4*)(emb + (size_t)n * kD + c0);
        fx4 ea = row[0];
        fx4 eb = row[1];

        float p0 = ea.x*w0a.x + ea.y*w0a.y + ea.z*w0a.z + ea.w*w0a.w
                 + eb.x*w0b.x + eb.y*w0b.y + eb.z*w0b.z + eb.w*w0b.w;
        float p1 = ea.x*w1a.x + ea.y*w1a.y + ea.z*w1a.z + ea.w*w1a.w
                 + eb.x*w1b.x + eb.y*w1b.y + eb.z*w1b.z + eb.w*w1b.w;
        float p2 = ea.x*w2a.x + ea.y*w2a.y + ea.z*w2a.z + ea.w*w2a.w
                 + eb.x*w2b.x + eb.y*w2b.y + eb.z*w2b.z + eb.w*w2b.w;
        float p3 = ea.x*w3a.x + ea.y*w3a.y + ea.z*w3a.z + ea.w*w3a.w
                 + eb.x*w3b.x + eb.y*w3b.y + eb.z*w3b.z + eb.w*w3b.w;

        // --- 5-shuffle transpose-reduce over the 16-lane group ---
        float sendU = (l & 1) ? p0 : p1;
        float keepU = (l & 1) ? p1 : p0;
        float u = keepU + __shfl_xor(sendU, 1);
        float sendW = (l & 1) ? p2 : p3;
        float keepW = (l & 1) ? p3 : p2;
        float w = keepW + __shfl_xor(sendW, 1);
        float sendX = (l & 2) ? u : w;
        float keepX = (l & 2) ? w : u;
        float x = keepX + __shfl_xor(sendX, 2);
        x += __shfl_xor(x, 4);
        x += __shfl_xor(x, 8);

        if (l < 4) h[n * 4 + l] = x;   // contiguous 16B per group
    }
}

// ---------------------------------------------------------------------------
// Phase 2: 4 edges per thread. In-wave dtype detection: every wave reads
// ei64[lane]; random indices < 100000 make an all-zero high-word pattern
// impossible for the int32-pair layout. Gathers 16B h-entries (1.6 MB table,
// L2-resident). Plain cached loads/stores throughout.
// ---------------------------------------------------------------------------
__global__ __launch_bounds__(256) void edge_attn(const void* __restrict__ eiv,
                                                 const float* __restrict__ h,
                                                 const float* __restrict__ b,
                                                 float* __restrict__ out) {
    const unsigned long long* ei64 = (const unsigned long long*)eiv;
    unsigned long long hi = ei64[threadIdx.x & 63] >> 32;
    const bool is64 = (__ballot(hi != 0ull) == 0ull);

    const int e4 = blockIdx.x * blockDim.x + threadIdx.x;   // quad index
    if (e4 >= kEdges / 4) return;

    int r[4], c[4];
    if (is64) {
        const unsigned long long* rr = ei64 + 4 * e4;
        const unsigned long long* cc = ei64 + kEdges + 4 * e4;
#pragma unroll
        for (int k = 0; k < 4; ++k) {
            r[k] = (int)rr[k];
            c[k] = (int)cc[k];
        }
    } else {
        const int* ei32 = (const int*)eiv;
#pragma unroll
        for (int k = 0; k < 4; ++k) {
            r[k] = ei32[4 * e4 + k];
            c[k] = ei32[kEdges + 4 * e4 + k];
        }
    }

    const fx4* h4 = (const fx4*)h;
    const float b0 = b[0], b1 = b[1];

    float res[8];
#pragma unroll
    for (int k = 0; k < 4; ++k) {
        fx4 hr = h4[r[k]];
        fx4 hc = h4[c[k]];
        float s0 = hr.x + hc.z + b0;
        float s1 = hr.y + hc.w + b1;
        float m  = fmaxf(s0, s1);
        float x0 = __expf(s0 - m);
        float x1 = __expf(s1 - m);
        float inv = 1.0f / (x0 + x1);
        res[2*k]     = x0 * inv;
        res[2*k + 1] = x1 * inv;
    }

    fx4* o4 = (fx4*)out;
    fx4 oa = {res[0], res[1], res[2], res[3]};
    fx4 ob = {res[4], res[5], res[6], res[7]};
    o4[2 * e4]     = oa;
    o4[2 * e4 + 1] = ob;
}

extern "C" void kernel_launch(void* const* d_in, const int* in_sizes, int n_in,
                              void* d_out, int out_size, void* d_ws, size_t ws_size,
                              hipStream_t stream) {
    const float* emb = (const float*)d_in[0];
    const void*  ei  = d_in[1];
    const float* W   = (const float*)d_in[2];
    const float* b   = (const float*)d_in[3];
    float* out = (float*)d_out;

    float* h = (float*)d_ws;   // 1.6 MB node table, 16B-aligned

    // ~4 nodes per 16-lane group (grid-stride)
    node_pre<<<(kNodes * 16 / 4 + 255) / 256, 256, 0, stream>>>(emb, W, h);

    // 4 edges per thread
    edge_attn<<<(kEdges / 4 + 255) / 256, 256, 0, stream>>>(ei, h, b, out);
}

// Round 7
// 32.537 us; speedup vs baseline: 7.7130x; 1.0253x over previous
//
#include <hip/hip_runtime.h>

static constexpr int kNodes = 100000;
static constexpr int kEdges = 1600000;
static constexpr int kD     = 128;

typedef float fx4 __attribute__((ext_vector_type(4)));

// ---------------------------------------------------------------------------
// Phase 1: per-node difference dots. Only s1-s0 matters for a 2-way softmax:
//   u[n] = emb[n] · (W[1]-W[0])[0:128]    (source-role contribution)
//   v[n] = emb[n] · (W[1]-W[0])[128:256]  (dest-role contribution)
// uv[2n]=u, uv[2n+1]=v. 16 lanes per node, 8 cols/lane, diff-weights in
// registers; 4-shuffle transpose-reduce lands u on even lanes, v on odd.
// One node per group (max TLP; 25k waves saturate HBM streaming).
// ---------------------------------------------------------------------------
__global__ __launch_bounds__(256) void node_pre(const float* __restrict__ emb,
                                                const float* __restrict__ W,
                                                float* __restrict__ uv) {
    const int l  = threadIdx.x & 15;   // lane within 16-group
    const int c0 = l * 8;

    // diff weights: du = (W1-W0)[c0..c0+8), dv = (W1-W0)[128+c0 .. )
    fx4 w0a = *(const fx4*)&W[c0],       w0b = *(const fx4*)&W[c0 + 4];
    fx4 w1a = *(const fx4*)&W[256 + c0], w1b = *(const fx4*)&W[256 + c0 + 4];
    fx4 dua = w1a - w0a, dub = w1b - w0b;
    fx4 w2a = *(const fx4*)&W[128 + c0], w2b = *(const fx4*)&W[128 + c0 + 4];
    fx4 w3a = *(const fx4*)&W[384 + c0], w3b = *(const fx4*)&W[384 + c0 + 4];
    fx4 dva = w3a - w2a, dvb = w3b - w2b;

    const int n = (blockIdx.x * blockDim.x + threadIdx.x) >> 4;
    if (n >= kNodes) return;

    const fx4* row = (const fx4*)(emb + (size_t)n * kD + c0);
    fx4 ea = row[0];
    fx4 eb = row[1];

    float pu = ea.x*dua.x + ea.y*dua.y + ea.z*dua.z + ea.w*dua.w
             + eb.x*dub.x + eb.y*dub.y + eb.z*dub.z + eb.w*dub.w;
    float pv = ea.x*dva.x + ea.y*dva.y + ea.z*dva.z + ea.w*dva.w
             + eb.x*dvb.x + eb.y*dvb.y + eb.z*dvb.z + eb.w*dvb.w;

    // transpose-reduce: even lanes end with u-sum, odd lanes with v-sum
    float keep = (l & 1) ? pv : pu;
    float send = (l & 1) ? pu : pv;
    float x = keep + __shfl_xor(send, 1);
    x += __shfl_xor(x, 2);
    x += __shfl_xor(x, 4);
    x += __shfl_xor(x, 8);

    if (l < 2) uv[n * 2 + l] = x;   // 8B per node
}

// ---------------------------------------------------------------------------
// Phase 2: 2 edges per thread. In-wave dtype detection (random indices
// < 100000 make an all-zero high-word pattern impossible for int32 pairs).
// d = u[r] + v[c] + (b1-b0);  p0 = 1/(1+e^d);  p1 = 1-p0.
// Gathers are 4B from an 800KB L2-resident table.
// ---------------------------------------------------------------------------
__global__ __launch_bounds__(256) void edge_attn(const void* __restrict__ eiv,
                                                 const float* __restrict__ uv,
                                                 const float* __restrict__ b,
                                                 float* __restrict__ out) {
    const unsigned long long* ei64 = (const unsigned long long*)eiv;
    unsigned long long hi = ei64[threadIdx.x & 63] >> 32;
    const bool is64 = (__ballot(hi != 0ull) == 0ull);

    const int e2 = blockIdx.x * blockDim.x + threadIdx.x;   // pair index
    if (e2 >= kEdges / 2) return;

    int r0, r1, c0i, c1i;
    if (is64) {
        const unsigned long long* rr = ei64 + 2 * e2;
        const unsigned long long* cc = ei64 + kEdges + 2 * e2;
        r0  = (int)rr[0]; r1  = (int)rr[1];
        c0i = (int)cc[0]; c1i = (int)cc[1];
    } else {
        const int* ei32 = (const int*)eiv;
        r0  = ei32[2 * e2];          r1  = ei32[2 * e2 + 1];
        c0i = ei32[kEdges + 2 * e2]; c1i = ei32[kEdges + 2 * e2 + 1];
    }

    const float db = b[1] - b[0];

    float d0 = uv[2 * r0] + uv[2 * c0i + 1] + db;
    float d1 = uv[2 * r1] + uv[2 * c1i + 1] + db;

    float p00 = __builtin_amdgcn_rcpf(1.0f + __expf(d0));
    float p10 = __builtin_amdgcn_rcpf(1.0f + __expf(d1));

    fx4 o = {p00, 1.0f - p00, p10, 1.0f - p10};
    ((fx4*)out)[e2] = o;
}

extern "C" void kernel_launch(void* const* d_in, const int* in_sizes, int n_in,
                              void* d_out, int out_size, void* d_ws, size_t ws_size,
                              hipStream_t stream) {
    const float* emb = (const float*)d_in[0];
    const void*  ei  = d_in[1];
    const float* W   = (const float*)d_in[2];
    const float* b   = (const float*)d_in[3];
    float* out = (float*)d_out;

    float* uv = (float*)d_ws;   // 800 KB node table

    // one node per 16-lane group
    node_pre<<<(kNodes * 16 + 255) / 256, 256, 0, stream>>>(emb, W, uv);

    // 2 edges per thread
    edge_attn<<<(kEdges / 2 + 255) / 256, 256, 0, stream>>>(ei, uv, b, out);
}